// Round 1
// baseline (839.857 us; speedup 1.0000x reference)
//
#include <hip/hip_runtime.h>

// Input  x: (8, 64, 512, 512) fp32  -> 512 images of 512x512
// Output: 4 planes (ll, hl, lh, hh), each (8, 64, 256, 256) fp32, flat-concatenated.
//
// One thread handles 2 horizontally-adjacent output pixels:
//   loads float4 from row 2r (a0,b0,a1,b1) and float4 from row 2r+1 (c0,d0,c1,d1),
//   writes float2 to each of the 4 output planes.

__global__ __launch_bounds__(256) void haar2d_kernel(
    const float* __restrict__ x, float* __restrict__ out)
{
    // total pairs = 512 imgs * 256 rows * 128 pairs = 16,777,216
    const unsigned tid = blockIdx.x * 256u + threadIdx.x;

    const unsigned c2  = tid & 127u;          // float2-pair column within output row
    const unsigned r   = (tid >> 7) & 255u;   // output row
    const unsigned img = tid >> 15;           // image index (0..511)

    // input: image base + row (2r) + 4*c2 floats; 16B aligned
    const size_t in_base = (size_t)img * (512u * 512u) + (size_t)(2u * r) * 512u + 4u * (size_t)c2;
    const float4 t = *reinterpret_cast<const float4*>(x + in_base);          // a0 b0 a1 b1
    const float4 u = *reinterpret_cast<const float4*>(x + in_base + 512u);   // c0 d0 c1 d1

    const float a0 = t.x, b0 = t.y, a1 = t.z, b1 = t.w;
    const float c0 = u.x, d0 = u.y, c1 = u.z, d1 = u.w;

    float2 ll, hl, lh, hh;
    ll.x = (a0 + b0 + c0 + d0) * 0.5f;
    ll.y = (a1 + b1 + c1 + d1) * 0.5f;
    hl.x = (a0 + b0 - c0 - d0) * 0.5f;
    hl.y = (a1 + b1 - c1 - d1) * 0.5f;
    lh.x = (a0 - b0 + c0 - d0) * 0.5f;
    lh.y = (a1 - b1 + c1 - d1) * 0.5f;
    hh.x = (a0 - b0 - c0 + d0) * 0.5f;
    hh.y = (a1 - b1 - c1 + d1) * 0.5f;

    // output planes: P = 512*256*256 = 33,554,432 floats each; in float2 units P/2 = 16,777,216
    const size_t P2 = 16777216u;
    const size_t o  = (size_t)img * (256u * 128u) + (size_t)r * 128u + c2; // float2 index in plane
    float2* o2 = reinterpret_cast<float2*>(out);
    o2[o]          = ll;
    o2[o + P2]     = hl;
    o2[o + 2 * P2] = lh;
    o2[o + 3 * P2] = hh;
}

extern "C" void kernel_launch(void* const* d_in, const int* in_sizes, int n_in,
                              void* d_out, int out_size, void* d_ws, size_t ws_size,
                              hipStream_t stream) {
    const float* x = (const float*)d_in[0];
    float* out = (float*)d_out;
    // 16,777,216 threads / 256 = 65,536 blocks
    haar2d_kernel<<<65536, 256, 0, stream>>>(x, out);
}